// Round 1
// baseline (957.204 us; speedup 1.0000x reference)
//
#include <hip/hip_runtime.h>

#define B_ 8
#define L_ 1024
#define HID_ 1024
#define D_ 64

// ---------------- K1: projections  out[r][d] = sum_h in[r][h]*W[h][d] + bias[d]
// grid (128, 3), block 256.  M-tile 64, N=64, K=1024.
__global__ __launch_bounds__(256) void proj_kernel(
    const float* __restrict__ query, const float* __restrict__ key, const float* __restrict__ value,
    const float* __restrict__ Wq, const float* __restrict__ bq,
    const float* __restrict__ Wk, const float* __restrict__ bk,
    const float* __restrict__ Wv, const float* __restrict__ bv,
    float* __restrict__ qp, float* __restrict__ kp, float* __restrict__ vp)
{
    const int which = blockIdx.y;
    const float* in   = which == 0 ? query : (which == 1 ? key : value);
    const float* W    = which == 0 ? Wq : (which == 1 ? Wk : Wv);
    const float* bias = which == 0 ? bq : (which == 1 ? bk : bv);
    float* out        = which == 0 ? qp : (which == 1 ? kp : vp);

    __shared__ float Xs[64][68];   // [row][k], padded (16B-aligned rows: 68*4=272)
    __shared__ float Ws[64][64];   // [k][d]

    const int t  = threadIdx.x;
    const int tx = t & 15;         // d/4
    const int ty = t >> 4;         // q/4 (0..15)
    const int r0 = blockIdx.x * 64;

    float acc[4][4] = {};
    for (int kk = 0; kk < HID_; kk += 64) {
        {
            const int r  = t >> 4;   // 0..15
            const int c4 = t & 15;
            #pragma unroll
            for (int i = 0; i < 4; i++) {
                float4 x = *(const float4*)(in + (size_t)(r0 + r + 16 * i) * HID_ + kk + 4 * c4);
                *(float4*)(&Xs[r + 16 * i][4 * c4]) = x;
                float4 w = *(const float4*)(W + (size_t)(kk + r + 16 * i) * D_ + 4 * c4);
                *(float4*)(&Ws[r + 16 * i][4 * c4]) = w;
            }
        }
        __syncthreads();
        #pragma unroll 8
        for (int k = 0; k < 64; k++) {
            float4 b4 = *(const float4*)(&Ws[k][4 * tx]);
            #pragma unroll
            for (int i = 0; i < 4; i++) {
                float a = Xs[4 * ty + i][k];
                acc[i][0] += a * b4.x;
                acc[i][1] += a * b4.y;
                acc[i][2] += a * b4.z;
                acc[i][3] += a * b4.w;
            }
        }
        __syncthreads();
    }
    float4 bb = *(const float4*)(bias + 4 * tx);
    #pragma unroll
    for (int i = 0; i < 4; i++) {
        float4 o;
        o.x = acc[i][0] + bb.x; o.y = acc[i][1] + bb.y;
        o.z = acc[i][2] + bb.z; o.w = acc[i][3] + bb.w;
        *(float4*)(out + (size_t)(r0 + 4 * ty + i) * D_ + 4 * tx) = o;
    }
}

// ---------------- K2: scores[b][q][k] = (qp[b,q]·(kp[b,k]+kb[q,k]))/8, masked
// grid (16 k-tiles, 64 q-tiles), block 256.  Each block: 16q x 64k x all 8 b.
// kb streamed through registers exactly once, reused for all 8 batches.
__global__ __launch_bounds__(256) void scores_kernel(
    const float* __restrict__ qp, const float* __restrict__ kp,
    const float* __restrict__ kb, const int* __restrict__ mask,
    float* __restrict__ scores)
{
    __shared__ float qs[8 * 16 * 64];   // [b][qi][d]
    const int t  = threadIdx.x;
    const int k0 = blockIdx.x * 64;
    const int q0 = blockIdx.y * 16;

    #pragma unroll
    for (int i = 0; i < 32; i++) {
        int flat = t + 256 * i;          // 0..8191
        int b   = flat >> 10;
        int rem = flat & 1023;           // qi*64 + d
        qs[flat] = qp[((size_t)b * L_ + q0 + (rem >> 6)) * D_ + (rem & 63)];
    }
    __syncthreads();

    const int klane = t & 63;
    const int kg    = k0 + klane;
    for (int pass = 0; pass < 4; pass++) {
        const int q  = pass * 4 + (t >> 6);
        const int qg = q0 + q;
        float acc[8] = {};
        const float* kbrow = kb + ((size_t)qg * L_ + kg) * D_;
        #pragma unroll 4
        for (int dc = 0; dc < 16; dc++) {
            float4 kb4 = *(const float4*)(kbrow + 4 * dc);
            #pragma unroll
            for (int b = 0; b < 8; b++) {
                float4 kp4 = *(const float4*)(kp + ((size_t)b * L_ + kg) * D_ + 4 * dc);
                float4 q4  = *(const float4*)(&qs[(b * 16 + q) * 64 + 4 * dc]);
                acc[b] += (kb4.x + kp4.x) * q4.x + (kb4.y + kp4.y) * q4.y +
                          (kb4.z + kp4.z) * q4.z + (kb4.w + kp4.w) * q4.w;
            }
        }
        #pragma unroll
        for (int b = 0; b < 8; b++) {
            float s = acc[b] * 0.125f;
            if (mask[b * L_ + kg] == 0) s = -1e9f;
            scores[((size_t)b * L_ + qg) * L_ + kg] = s;
        }
    }
}

// ---------------- K3: row softmax in-place.  grid 8192, block 256 (4 floats/thread)
__global__ __launch_bounds__(256) void softmax_kernel(float* __restrict__ scores)
{
    float* p = scores + (size_t)blockIdx.x * L_;
    const int t = threadIdx.x;
    float4 x = *(const float4*)(p + 4 * t);

    float m = fmaxf(fmaxf(x.x, x.y), fmaxf(x.z, x.w));
    #pragma unroll
    for (int off = 32; off; off >>= 1) m = fmaxf(m, __shfl_down(m, off));
    __shared__ float red[4];
    if ((t & 63) == 0) red[t >> 6] = m;
    __syncthreads();
    float M = fmaxf(fmaxf(red[0], red[1]), fmaxf(red[2], red[3]));

    float e0 = __expf(x.x - M), e1 = __expf(x.y - M);
    float e2 = __expf(x.z - M), e3 = __expf(x.w - M);
    float s = e0 + e1 + e2 + e3;
    #pragma unroll
    for (int off = 32; off; off >>= 1) s += __shfl_down(s, off);
    __shared__ float red2[4];
    if ((t & 63) == 0) red2[t >> 6] = s;
    __syncthreads();
    float inv = 1.0f / (red2[0] + red2[1] + red2[2] + red2[3]);

    float4 o; o.x = e0 * inv; o.y = e1 * inv; o.z = e2 * inv; o.w = e3 * inv;
    *(float4*)(p + 4 * t) = o;
}

// ---------------- K4a: out[b][q][d] = sum_k w[b][q][k]*vp[b][k][d]
// grid (32 q-tiles, 8 b), block 256.  M=32(q), N=64(d), K=1024.
__global__ __launch_bounds__(256) void pv_kernel(
    const float* __restrict__ w, const float* __restrict__ vp, float* __restrict__ out)
{
    const int b  = blockIdx.y;
    const int q0 = blockIdx.x * 32;
    __shared__ float ws_[32][68];
    __shared__ float vs[64][64];
    const int t  = threadIdx.x;
    const int tx = t & 15;
    const int ty = t >> 4;    // 0..15 -> 2 q rows each
    float acc[2][4] = {};
    for (int kk = 0; kk < L_; kk += 64) {
        #pragma unroll
        for (int i = 0; i < 2; i++) {
            int f4 = t + 256 * i;            // 0..511 float4s of the 32x64 w tile
            int qi = f4 >> 4, kc = f4 & 15;
            float4 x = *(const float4*)(w + ((size_t)b * L_ + q0 + qi) * L_ + kk + 4 * kc);
            *(float4*)(&ws_[qi][4 * kc]) = x;
        }
        #pragma unroll
        for (int i = 0; i < 4; i++) {
            int f4 = t + 256 * i;            // 0..1023 float4s of the 64x64 vp tile
            int kr = f4 >> 4, dc = f4 & 15;
            float4 x = *(const float4*)(vp + ((size_t)b * L_ + kk + kr) * D_ + 4 * dc);
            *(float4*)(&vs[kr][4 * dc]) = x;
        }
        __syncthreads();
        #pragma unroll 8
        for (int k = 0; k < 64; k++) {
            float4 v4 = *(const float4*)(&vs[k][4 * tx]);
            float a0 = ws_[2 * ty][k], a1 = ws_[2 * ty + 1][k];
            acc[0][0] += a0 * v4.x; acc[0][1] += a0 * v4.y;
            acc[0][2] += a0 * v4.z; acc[0][3] += a0 * v4.w;
            acc[1][0] += a1 * v4.x; acc[1][1] += a1 * v4.y;
            acc[1][2] += a1 * v4.z; acc[1][3] += a1 * v4.w;
        }
        __syncthreads();
    }
    #pragma unroll
    for (int i = 0; i < 2; i++) {
        float4 o; o.x = acc[i][0]; o.y = acc[i][1]; o.z = acc[i][2]; o.w = acc[i][3];
        *(float4*)(out + ((size_t)b * L_ + q0 + 2 * ty + i) * D_ + 4 * tx) = o;
    }
}

// ---------------- K4b: out[b][q][d] += sum_k w[b][q][k]*vb[q][k][d]
// grid 1024 (one q per block), block 256: thread = (d lane, k-slice).
// vb streamed from HBM exactly once; w row transposed in LDS ([k][b], stride 12
// keeps the two float4 reads 16B-aligned) so the 8 batch weights come from 2
// broadcast ds_read_b128.
__global__ __launch_bounds__(256) void vbias_kernel(
    const float* __restrict__ w, const float* __restrict__ vb, float* __restrict__ out)
{
    const int q = blockIdx.x;
    __shared__ float wt[L_ * 12];        // [k][b], stride 12 floats (48KB)
    __shared__ float part[4 * 64 * 8];   // [ks][d][b] (8KB)
    const int t = threadIdx.x;

    #pragma unroll
    for (int i = 0; i < 32; i++) {
        int flat = t + 256 * i;          // 0..8191
        int b = flat >> 10, k = flat & 1023;
        wt[k * 12 + b] = w[((size_t)b * L_ + q) * L_ + k];
    }
    __syncthreads();

    const int d  = t & 63;
    const int ks = t >> 6;               // 0..3, 256 k each
    float acc[8] = {};
    const float* vbp = vb + ((size_t)q * L_ + ks * 256) * D_ + d;
    #pragma unroll 4
    for (int j = 0; j < 256; j++) {
        float v = vbp[(size_t)j * D_];
        int k = ks * 256 + j;
        float4 w0 = *(const float4*)(&wt[k * 12]);
        float4 w1 = *(const float4*)(&wt[k * 12 + 4]);
        acc[0] += v * w0.x; acc[1] += v * w0.y; acc[2] += v * w0.z; acc[3] += v * w0.w;
        acc[4] += v * w1.x; acc[5] += v * w1.y; acc[6] += v * w1.z; acc[7] += v * w1.w;
    }
    float4* pp = (float4*)&part[(ks * 64 + d) * 8];
    pp[0] = make_float4(acc[0], acc[1], acc[2], acc[3]);
    pp[1] = make_float4(acc[4], acc[5], acc[6], acc[7]);
    __syncthreads();
    if (t < 64) {
        #pragma unroll
        for (int bb = 0; bb < 8; bb++) {
            float s = part[(0 * 64 + t) * 8 + bb] + part[(1 * 64 + t) * 8 + bb] +
                      part[(2 * 64 + t) * 8 + bb] + part[(3 * 64 + t) * 8 + bb];
            size_t idx = ((size_t)bb * L_ + q) * D_ + t;
            out[idx] += s;   // K4a already wrote values_1
        }
    }
}

extern "C" void kernel_launch(void* const* d_in, const int* in_sizes, int n_in,
                              void* d_out, int out_size, void* d_ws, size_t ws_size,
                              hipStream_t stream)
{
    const float* query = (const float*)d_in[0];
    const float* key   = (const float*)d_in[1];
    const float* value = (const float*)d_in[2];
    const float* kb    = (const float*)d_in[3];
    const float* vb    = (const float*)d_in[4];
    const float* Wq    = (const float*)d_in[5];
    const float* bq    = (const float*)d_in[6];
    const float* Wk    = (const float*)d_in[7];
    const float* bk    = (const float*)d_in[8];
    const float* Wv    = (const float*)d_in[9];
    const float* bv    = (const float*)d_in[10];
    const int*   mask  = (const int*)d_in[11];
    float* out = (float*)d_out;

    float* ws = (float*)d_ws;
    const size_t PROJ = (size_t)B_ * L_ * D_;        // 524288 floats
    float* qp     = ws;
    float* kp     = ws + PROJ;
    float* vp     = ws + 2 * PROJ;
    float* scores = ws + 3 * PROJ;                   // 8*1024*1024 floats (32MB)

    proj_kernel<<<dim3(128, 3), 256, 0, stream>>>(query, key, value,
                                                  Wq, bq, Wk, bk, Wv, bv,
                                                  qp, kp, vp);
    scores_kernel<<<dim3(16, 64), 256, 0, stream>>>(qp, kp, kb, mask, scores);
    softmax_kernel<<<B_ * L_, 256, 0, stream>>>(scores);
    pv_kernel<<<dim3(32, 8), 256, 0, stream>>>(scores, vp, out);
    vbias_kernel<<<L_, 256, 0, stream>>>(scores, vb, out);
}

// Round 2
// 713.001 us; speedup vs baseline: 1.3425x; 1.3425x over previous
//
#include <hip/hip_runtime.h>

#define B_ 8
#define L_ 1024
#define HID_ 1024
#define D_ 64

typedef short bf16x8 __attribute__((ext_vector_type(8)));
typedef float f32x4 __attribute__((ext_vector_type(4)));

__device__ inline short f2bf(float f) {
    unsigned u = __builtin_bit_cast(unsigned, f);
    unsigned r = (u + 0x7fffu + ((u >> 16) & 1u)) >> 16;   // RNE
    return (short)r;
}

// ---------------- K1: projections  out[r][d] = sum_h in[r][h]*W[h][d] + bias[d]
__global__ __launch_bounds__(256) void proj_kernel(
    const float* __restrict__ query, const float* __restrict__ key, const float* __restrict__ value,
    const float* __restrict__ Wq, const float* __restrict__ bq,
    const float* __restrict__ Wk, const float* __restrict__ bk,
    const float* __restrict__ Wv, const float* __restrict__ bv,
    float* __restrict__ qp, float* __restrict__ kp, float* __restrict__ vp)
{
    const int which = blockIdx.y;
    const float* in   = which == 0 ? query : (which == 1 ? key : value);
    const float* W    = which == 0 ? Wq : (which == 1 ? Wk : Wv);
    const float* bias = which == 0 ? bq : (which == 1 ? bk : bv);
    float* out        = which == 0 ? qp : (which == 1 ? kp : vp);

    __shared__ float Xs[64][68];
    __shared__ float Ws[64][64];

    const int t  = threadIdx.x;
    const int tx = t & 15;
    const int ty = t >> 4;
    const int r0 = blockIdx.x * 64;

    float acc[4][4] = {};
    for (int kk = 0; kk < HID_; kk += 64) {
        {
            const int r  = t >> 4;
            const int c4 = t & 15;
            #pragma unroll
            for (int i = 0; i < 4; i++) {
                float4 x = *(const float4*)(in + (size_t)(r0 + r + 16 * i) * HID_ + kk + 4 * c4);
                *(float4*)(&Xs[r + 16 * i][4 * c4]) = x;
                float4 w = *(const float4*)(W + (size_t)(kk + r + 16 * i) * D_ + 4 * c4);
                *(float4*)(&Ws[r + 16 * i][4 * c4]) = w;
            }
        }
        __syncthreads();
        #pragma unroll 8
        for (int k = 0; k < 64; k++) {
            float4 b4 = *(const float4*)(&Ws[k][4 * tx]);
            #pragma unroll
            for (int i = 0; i < 4; i++) {
                float a = Xs[4 * ty + i][k];
                acc[i][0] += a * b4.x;
                acc[i][1] += a * b4.y;
                acc[i][2] += a * b4.z;
                acc[i][3] += a * b4.w;
            }
        }
        __syncthreads();
    }
    float4 bb = *(const float4*)(bias + 4 * tx);
    #pragma unroll
    for (int i = 0; i < 4; i++) {
        float4 o;
        o.x = acc[i][0] + bb.x; o.y = acc[i][1] + bb.y;
        o.z = acc[i][2] + bb.z; o.w = acc[i][3] + bb.w;
        *(float4*)(out + (size_t)(r0 + 4 * ty + i) * D_ + 4 * tx) = o;
    }
}

// ---------------- K2: s1[b][q][k] = (qp[b,q,:]·kp[b,k,:])*0.125, masked  (fp32)
// grid (8 kt, 8 qt, 8 b), block 256.  128q x 128k tile, K=64.
// thread (tx,ty) owns q = q0+ty+16i, k = k0+tx+16j (stride-16 interleave keeps
// LDS reads conflict-light: qs banks 4*ty, ks banks 4*tx -> <=2-way).
__global__ __launch_bounds__(256) void attn1_kernel(
    const float* __restrict__ qp, const float* __restrict__ kp,
    const int* __restrict__ mask, float* __restrict__ s1)
{
    const int b  = blockIdx.z;
    const int q0 = blockIdx.y * 128;
    const int k0 = blockIdx.x * 128;
    __shared__ float qs[128][68];
    __shared__ float ks[128][68];
    const int t = threadIdx.x;
    {
        const int row = t >> 4;
        const int c4  = t & 15;
        #pragma unroll
        for (int i = 0; i < 8; i++) {
            int r = row + 16 * i;
            *(float4*)&qs[r][c4 * 4] = *(const float4*)(qp + ((size_t)b * L_ + q0 + r) * D_ + c4 * 4);
            *(float4*)&ks[r][c4 * 4] = *(const float4*)(kp + ((size_t)b * L_ + k0 + r) * D_ + c4 * 4);
        }
    }
    __syncthreads();
    const int tx = t & 15, ty = t >> 4;
    float acc[8][8] = {};
    for (int d4 = 0; d4 < 16; d4++) {
        float4 qv[8], kv[8];
        #pragma unroll
        for (int i = 0; i < 8; i++) qv[i] = *(const float4*)&qs[ty + 16 * i][d4 * 4];
        #pragma unroll
        for (int j = 0; j < 8; j++) kv[j] = *(const float4*)&ks[tx + 16 * j][d4 * 4];
        #pragma unroll
        for (int i = 0; i < 8; i++)
            #pragma unroll
            for (int j = 0; j < 8; j++)
                acc[i][j] += qv[i].x * kv[j].x + qv[i].y * kv[j].y +
                             qv[i].z * kv[j].z + qv[i].w * kv[j].w;
    }
    #pragma unroll
    for (int j = 0; j < 8; j++) {
        int kg = k0 + tx + 16 * j;
        bool live = mask[b * L_ + kg] != 0;
        #pragma unroll
        for (int i = 0; i < 8; i++) {
            int qg = q0 + ty + 16 * i;
            s1[((size_t)b * L_ + qg) * L_ + kg] = live ? acc[i][j] * 0.125f : -1e9f;
        }
    }
}

// ---------------- K3: fused attn2(MFMA-bf16) + s1-add + softmax + values
// grid 512 (2 q per block), block 512 (8 waves).  LDS: sc[2][8][1032] + qbf.
#define KS_ 1032
__global__ __launch_bounds__(512) void row_kernel(
    const float* __restrict__ qp, const float* __restrict__ vp,
    const float* __restrict__ kb, const float* __restrict__ vb,
    const float* __restrict__ s1, float* __restrict__ out)
{
    __shared__ float sc[2 * 8 * KS_];     // [q][b][k], padded stride 1032
    __shared__ short qbf[2 * 16 * 64];    // [q][b(16, 8..15 zero)][d] bf16, pre-scaled 0.125
    const int t = threadIdx.x;
    const int wave = t >> 6, lane = t & 63;
    const int q0 = blockIdx.x * 2;

    // prologue: build scaled-bf16 q vectors
    #pragma unroll
    for (int i = 0; i < 4; i++) {
        int idx = t + 512 * i;            // 0..2047
        int d = idx & 63, bq = idx >> 6;
        int b = bq & 15, q = bq >> 4;
        float v = (b < 8) ? 0.125f * qp[((size_t)b * L_ + q0 + q) * D_ + d] : 0.0f;
        qbf[idx] = f2bf(v);
    }
    __syncthreads();

    // phase A1: s2 = q·kb^T via MFMA; kb fragments straight from global.
    // job = (q, 16-k tile); D[row=k_local][col=b].
    for (int job = wave; job < 128; job += 8) {
        int q = job >> 6, kt = job & 63;
        int k0 = kt * 16;
        const float* abase = kb + ((size_t)(q0 + q) * L_ + k0 + (lane & 15)) * D_ + (lane >> 4) * 8;
        f32x4 acc = {0.f, 0.f, 0.f, 0.f};
        #pragma unroll
        for (int h = 0; h < 2; h++) {
            float4 x0 = *(const float4*)(abase + h * 32);
            float4 x1 = *(const float4*)(abase + h * 32 + 4);
            bf16x8 a;
            a[0] = f2bf(x0.x); a[1] = f2bf(x0.y); a[2] = f2bf(x0.z); a[3] = f2bf(x0.w);
            a[4] = f2bf(x1.x); a[5] = f2bf(x1.y); a[6] = f2bf(x1.z); a[7] = f2bf(x1.w);
            bf16x8 bq = *(const bf16x8*)&qbf[(q * 16 + (lane & 15)) * 64 + h * 32 + (lane >> 4) * 8];
            acc = __builtin_amdgcn_mfma_f32_16x16x32_bf16(a, bq, acc, 0, 0, 0);
        }
        int b = lane & 15;
        if (b < 8) {
            float* dst = &sc[(q * 8 + b) * KS_ + k0 + (lane >> 4) * 4];
            dst[0] = acc[0]; dst[1] = acc[1]; dst[2] = acc[2]; dst[3] = acc[3];
        }
    }
    __syncthreads();

    // phase A2: += s1 (coalesced dwordx4 reads)
    #pragma unroll
    for (int i = 0; i < 8; i++) {
        int idx = t + 512 * i;            // 0..4095 float4s
        int c4 = idx & 255;
        int row = idx >> 8;               // b = row&7, q = row>>3
        int b = row & 7, q = row >> 3;
        float4 s = *(const float4*)(s1 + ((size_t)b * L_ + q0 + q) * L_ + c4 * 4);
        float* dst = &sc[(q * 8 + b) * KS_ + c4 * 4];
        float4 cur = *(float4*)dst;
        cur.x += s.x; cur.y += s.y; cur.z += s.z; cur.w += s.w;
        *(float4*)dst = cur;
    }
    __syncthreads();

    // phase B: softmax, one (q,b) row entirely inside one wave
    for (int r = wave; r < 16; r += 8) {
        float* rowp = &sc[r * KS_];
        float4 x[4];
        float m = -1e30f;
        #pragma unroll
        for (int j = 0; j < 4; j++) {
            x[j] = *(const float4*)&rowp[lane * 4 + 256 * j];
            m = fmaxf(m, fmaxf(fmaxf(x[j].x, x[j].y), fmaxf(x[j].z, x[j].w)));
        }
        #pragma unroll
        for (int off = 32; off; off >>= 1) m = fmaxf(m, __shfl_xor(m, off));
        float s = 0.f;
        #pragma unroll
        for (int j = 0; j < 4; j++) {
            x[j].x = __expf(x[j].x - m); x[j].y = __expf(x[j].y - m);
            x[j].z = __expf(x[j].z - m); x[j].w = __expf(x[j].w - m);
            s += x[j].x + x[j].y + x[j].z + x[j].w;
        }
        #pragma unroll
        for (int off = 32; off; off >>= 1) s += __shfl_xor(s, off);
        float inv = 1.0f / s;
        #pragma unroll
        for (int j = 0; j < 4; j++) {
            x[j].x *= inv; x[j].y *= inv; x[j].z *= inv; x[j].w *= inv;
            *(float4*)&rowp[lane * 4 + 256 * j] = x[j];
        }
    }
    __syncthreads();

    // phase C: out[b,q,d] += sum_k w[b,q,k]*(vp[b,k,d] + vb[q,k,d])
    // wave -> (q, k-quarter); lane = (k_local=lane>>4, d4=lane&15).
    {
        const int q  = wave >> 2;
        const int kq = (wave & 3) * 256;
        const int kl = lane >> 4;
        const int d4 = lane & 15;
        float acc[8][4] = {};
        const float* vbbase = vb + ((size_t)(q0 + q) * L_ + kq + kl) * D_ + d4 * 4;
        #pragma unroll 2
        for (int j = 0; j < 64; j++) {
            int k = kq + j * 4 + kl;
            float4 vb4 = *(const float4*)(vbbase + (size_t)j * 4 * D_);
            #pragma unroll
            for (int b = 0; b < 8; b++) {
                float4 vp4 = *(const float4*)(vp + ((size_t)b * L_ + k) * D_ + d4 * 4);
                float wgt = sc[(q * 8 + b) * KS_ + k];
                acc[b][0] += wgt * (vb4.x + vp4.x);
                acc[b][1] += wgt * (vb4.y + vp4.y);
                acc[b][2] += wgt * (vb4.z + vp4.z);
                acc[b][3] += wgt * (vb4.w + vp4.w);
            }
        }
        #pragma unroll
        for (int b = 0; b < 8; b++)
            #pragma unroll
            for (int j = 0; j < 4; j++) {
                float v = acc[b][j];
                v += __shfl_down(v, 32);
                v += __shfl_down(v, 16);
                acc[b][j] = v;
            }
        if (lane < 16) {
            #pragma unroll
            for (int b = 0; b < 8; b++)
                #pragma unroll
                for (int j = 0; j < 4; j++)
                    atomicAdd(out + ((size_t)b * L_ + q0 + q) * D_ + d4 * 4 + j, acc[b][j]);
        }
    }
}

extern "C" void kernel_launch(void* const* d_in, const int* in_sizes, int n_in,
                              void* d_out, int out_size, void* d_ws, size_t ws_size,
                              hipStream_t stream)
{
    const float* query = (const float*)d_in[0];
    const float* key   = (const float*)d_in[1];
    const float* value = (const float*)d_in[2];
    const float* kb    = (const float*)d_in[3];
    const float* vb    = (const float*)d_in[4];
    const float* Wq    = (const float*)d_in[5];
    const float* bq    = (const float*)d_in[6];
    const float* Wk    = (const float*)d_in[7];
    const float* bk    = (const float*)d_in[8];
    const float* Wv    = (const float*)d_in[9];
    const float* bv    = (const float*)d_in[10];
    const int*   mask  = (const int*)d_in[11];
    float* out = (float*)d_out;

    float* ws = (float*)d_ws;
    const size_t PROJ = (size_t)B_ * L_ * D_;
    float* qp = ws;
    float* kp = ws + PROJ;
    float* vp = ws + 2 * PROJ;
    float* s1 = ws + 3 * PROJ;            // 8*1024*1024 floats = 32MB

    hipMemsetAsync(d_out, 0, (size_t)B_ * L_ * D_ * sizeof(float), stream);
    proj_kernel<<<dim3(128, 3), 256, 0, stream>>>(query, key, value,
                                                  Wq, bq, Wk, bk, Wv, bv,
                                                  qp, kp, vp);
    attn1_kernel<<<dim3(8, 8, 8), 256, 0, stream>>>(qp, kp, mask, s1);
    row_kernel<<<512, 512, 0, stream>>>(qp, vp, kb, vb, s1, out);
}

// Round 3
// 691.445 us; speedup vs baseline: 1.3844x; 1.0312x over previous
//
#include <hip/hip_runtime.h>

#define B_ 8
#define L_ 1024
#define HID_ 1024
#define D_ 64

typedef short bf16x8 __attribute__((ext_vector_type(8)));
typedef float f32x4 __attribute__((ext_vector_type(4)));

__device__ inline short f2bf(float f) {
    unsigned u = __builtin_bit_cast(unsigned, f);
    unsigned r = (u + 0x7fffu + ((u >> 16) & 1u)) >> 16;   // RNE
    return (short)r;
}

// ---------------- K1: projections  out[r][d] = sum_h in[r][h]*W[h][d] + bias[d]
__global__ __launch_bounds__(256) void proj_kernel(
    const float* __restrict__ query, const float* __restrict__ key, const float* __restrict__ value,
    const float* __restrict__ Wq, const float* __restrict__ bq,
    const float* __restrict__ Wk, const float* __restrict__ bk,
    const float* __restrict__ Wv, const float* __restrict__ bv,
    float* __restrict__ qp, float* __restrict__ kp, float* __restrict__ vp)
{
    const int which = blockIdx.y;
    const float* in   = which == 0 ? query : (which == 1 ? key : value);
    const float* W    = which == 0 ? Wq : (which == 1 ? Wk : Wv);
    const float* bias = which == 0 ? bq : (which == 1 ? bk : bv);
    float* out        = which == 0 ? qp : (which == 1 ? kp : vp);

    __shared__ float Xs[64][68];
    __shared__ float Ws[64][64];

    const int t  = threadIdx.x;
    const int tx = t & 15;
    const int ty = t >> 4;
    const int r0 = blockIdx.x * 64;

    float acc[4][4] = {};
    for (int kk = 0; kk < HID_; kk += 64) {
        {
            const int r  = t >> 4;
            const int c4 = t & 15;
            #pragma unroll
            for (int i = 0; i < 4; i++) {
                float4 x = *(const float4*)(in + (size_t)(r0 + r + 16 * i) * HID_ + kk + 4 * c4);
                *(float4*)(&Xs[r + 16 * i][4 * c4]) = x;
                float4 w = *(const float4*)(W + (size_t)(kk + r + 16 * i) * D_ + 4 * c4);
                *(float4*)(&Ws[r + 16 * i][4 * c4]) = w;
            }
        }
        __syncthreads();
        #pragma unroll 8
        for (int k = 0; k < 64; k++) {
            float4 b4 = *(const float4*)(&Ws[k][4 * tx]);
            #pragma unroll
            for (int i = 0; i < 4; i++) {
                float a = Xs[4 * ty + i][k];
                acc[i][0] += a * b4.x;
                acc[i][1] += a * b4.y;
                acc[i][2] += a * b4.z;
                acc[i][3] += a * b4.w;
            }
        }
        __syncthreads();
    }
    float4 bb = *(const float4*)(bias + 4 * tx);
    #pragma unroll
    for (int i = 0; i < 4; i++) {
        float4 o;
        o.x = acc[i][0] + bb.x; o.y = acc[i][1] + bb.y;
        o.z = acc[i][2] + bb.z; o.w = acc[i][3] + bb.w;
        *(float4*)(out + (size_t)(r0 + 4 * ty + i) * D_ + 4 * tx) = o;
    }
}

// ---------------- K2: s1[b][q][k] = (qp[b,q,:]·kp[b,k,:])*0.125, masked  (fp32)
__global__ __launch_bounds__(256) void attn1_kernel(
    const float* __restrict__ qp, const float* __restrict__ kp,
    const int* __restrict__ mask, float* __restrict__ s1)
{
    const int b  = blockIdx.z;
    const int q0 = blockIdx.y * 128;
    const int k0 = blockIdx.x * 128;
    __shared__ float qs[128][68];
    __shared__ float ks[128][68];
    const int t = threadIdx.x;
    {
        const int row = t >> 4;
        const int c4  = t & 15;
        #pragma unroll
        for (int i = 0; i < 8; i++) {
            int r = row + 16 * i;
            *(float4*)&qs[r][c4 * 4] = *(const float4*)(qp + ((size_t)b * L_ + q0 + r) * D_ + c4 * 4);
            *(float4*)&ks[r][c4 * 4] = *(const float4*)(kp + ((size_t)b * L_ + k0 + r) * D_ + c4 * 4);
        }
    }
    __syncthreads();
    const int tx = t & 15, ty = t >> 4;
    float acc[8][8] = {};
    for (int d4 = 0; d4 < 16; d4++) {
        float4 qv[8], kv[8];
        #pragma unroll
        for (int i = 0; i < 8; i++) qv[i] = *(const float4*)&qs[ty + 16 * i][d4 * 4];
        #pragma unroll
        for (int j = 0; j < 8; j++) kv[j] = *(const float4*)&ks[tx + 16 * j][d4 * 4];
        #pragma unroll
        for (int i = 0; i < 8; i++)
            #pragma unroll
            for (int j = 0; j < 8; j++)
                acc[i][j] += qv[i].x * kv[j].x + qv[i].y * kv[j].y +
                             qv[i].z * kv[j].z + qv[i].w * kv[j].w;
    }
    #pragma unroll
    for (int j = 0; j < 8; j++) {
        int kg = k0 + tx + 16 * j;
        bool live = mask[b * L_ + kg] != 0;
        #pragma unroll
        for (int i = 0; i < 8; i++) {
            int qg = q0 + ty + 16 * i;
            s1[((size_t)b * L_ + qg) * L_ + kg] = live ? acc[i][j] * 0.125f : -1e9f;
        }
    }
}

// ---------------- K3: fused attn2(MFMA-bf16) + s1-add + softmax + vb-term
// grid 512 (2 q per block), block 512 (8 waves).
// Softmaxed weights are written back IN-PLACE over s1 (each block owns its
// 2 q rows exclusively), consumed later by pv_kernel.  out gets the vb term
// (exclusive ownership, no atomics).  LDS 70KB -> 2 blocks/CU.
#define KS_ 1032
__global__ __launch_bounds__(512) void row_kernel(
    const float* __restrict__ qp, const float* __restrict__ kb,
    const float* __restrict__ vb, float* __restrict__ s1w,
    float* __restrict__ out)
{
    __shared__ float sc[2 * 8 * KS_];     // [q][b][k] scores; later aliased for partials
    __shared__ short qbf[2 * 16 * 64];    // [q][b(16, 8..15 zero)][d] bf16, pre-scaled 0.125
    const int t = threadIdx.x;
    const int wave = t >> 6, lane = t & 63;
    const int q0 = blockIdx.x * 2;

    // prologue: scaled-bf16 q vectors
    #pragma unroll
    for (int i = 0; i < 4; i++) {
        int idx = t + 512 * i;            // 0..2047
        int d = idx & 63, bq = idx >> 6;
        int b = bq & 15, q = bq >> 4;
        float v = (b < 8) ? 0.125f * qp[((size_t)b * L_ + q0 + q) * D_ + d] : 0.0f;
        qbf[idx] = f2bf(v);
    }
    __syncthreads();

    // phase A1: s2 = q·kb^T via MFMA, kb fragments straight from global
    for (int job = wave; job < 128; job += 8) {
        int q = job >> 6, kt = job & 63;
        int k0 = kt * 16;
        const float* abase = kb + ((size_t)(q0 + q) * L_ + k0 + (lane & 15)) * D_ + (lane >> 4) * 8;
        f32x4 acc = {0.f, 0.f, 0.f, 0.f};
        #pragma unroll
        for (int h = 0; h < 2; h++) {
            float4 x0 = *(const float4*)(abase + h * 32);
            float4 x1 = *(const float4*)(abase + h * 32 + 4);
            bf16x8 a;
            a[0] = f2bf(x0.x); a[1] = f2bf(x0.y); a[2] = f2bf(x0.z); a[3] = f2bf(x0.w);
            a[4] = f2bf(x1.x); a[5] = f2bf(x1.y); a[6] = f2bf(x1.z); a[7] = f2bf(x1.w);
            bf16x8 bq = *(const bf16x8*)&qbf[(q * 16 + (lane & 15)) * 64 + h * 32 + (lane >> 4) * 8];
            acc = __builtin_amdgcn_mfma_f32_16x16x32_bf16(a, bq, acc, 0, 0, 0);
        }
        int b = lane & 15;
        if (b < 8) {
            float* dst = &sc[(q * 8 + b) * KS_ + k0 + (lane >> 4) * 4];
            dst[0] = acc[0]; dst[1] = acc[1]; dst[2] = acc[2]; dst[3] = acc[3];
        }
    }
    __syncthreads();

    // phase A2: += s1
    #pragma unroll
    for (int i = 0; i < 8; i++) {
        int idx = t + 512 * i;            // 0..4095 float4s
        int c4 = idx & 255;
        int row = idx >> 8;
        int b = row & 7, q = row >> 3;
        float4 s = *(const float4*)(s1w + ((size_t)b * L_ + q0 + q) * L_ + c4 * 4);
        float* dst = &sc[(q * 8 + b) * KS_ + c4 * 4];
        float4 cur = *(float4*)dst;
        cur.x += s.x; cur.y += s.y; cur.z += s.z; cur.w += s.w;
        *(float4*)dst = cur;
    }
    __syncthreads();

    // phase B: softmax per (q,b) row inside one wave; write w back over s1
    for (int r = wave; r < 16; r += 8) {
        int q = r >> 3, b = r & 7;
        float* rowp = &sc[r * KS_];
        float* wrow = s1w + ((size_t)b * L_ + q0 + q) * L_;
        float4 x[4];
        float m = -1e30f;
        #pragma unroll
        for (int j = 0; j < 4; j++) {
            x[j] = *(const float4*)&rowp[lane * 4 + 256 * j];
            m = fmaxf(m, fmaxf(fmaxf(x[j].x, x[j].y), fmaxf(x[j].z, x[j].w)));
        }
        #pragma unroll
        for (int off = 32; off; off >>= 1) m = fmaxf(m, __shfl_xor(m, off));
        float s = 0.f;
        #pragma unroll
        for (int j = 0; j < 4; j++) {
            x[j].x = __expf(x[j].x - m); x[j].y = __expf(x[j].y - m);
            x[j].z = __expf(x[j].z - m); x[j].w = __expf(x[j].w - m);
            s += x[j].x + x[j].y + x[j].z + x[j].w;
        }
        #pragma unroll
        for (int off = 32; off; off >>= 1) s += __shfl_xor(s, off);
        float inv = 1.0f / s;
        #pragma unroll
        for (int j = 0; j < 4; j++) {
            x[j].x *= inv; x[j].y *= inv; x[j].z *= inv; x[j].w *= inv;
            *(float4*)&rowp[lane * 4 + 256 * j] = x[j];
            *(float4*)&wrow[lane * 4 + 256 * j] = x[j];
        }
    }
    __syncthreads();

    // phase C: vb term only.  wave -> (q, k-quarter); lane = (kl=lane>>4, d4=lane&15)
    {
        const int q  = wave >> 2;
        const int kqi = wave & 3;
        const int kq = kqi * 256;
        const int kl = lane >> 4;
        const int d4 = lane & 15;
        float acc[8][4] = {};
        const float* vbbase = vb + ((size_t)(q0 + q) * L_ + kq + kl) * D_ + d4 * 4;
        #pragma unroll 4
        for (int j = 0; j < 64; j++) {
            int k = kq + j * 4 + kl;
            float4 vb4 = *(const float4*)(vbbase + (size_t)j * 4 * D_);
            #pragma unroll
            for (int b = 0; b < 8; b++) {
                float wgt = sc[(q * 8 + b) * KS_ + k];
                acc[b][0] += wgt * vb4.x;
                acc[b][1] += wgt * vb4.y;
                acc[b][2] += wgt * vb4.z;
                acc[b][3] += wgt * vb4.w;
            }
        }
        #pragma unroll
        for (int b = 0; b < 8; b++)
            #pragma unroll
            for (int j = 0; j < 4; j++) {
                float v = acc[b][j];
                v += __shfl_down(v, 32);
                v += __shfl_down(v, 16);
                acc[b][j] = v;
            }
        __syncthreads();                 // all sc weight reads done -> safe to alias
        float* part = sc;                // part[((q*4+kqi)*8+b)*64 + d]
        if (lane < 16) {
            #pragma unroll
            for (int b = 0; b < 8; b++) {
                float4 o; o.x = acc[b][0]; o.y = acc[b][1]; o.z = acc[b][2]; o.w = acc[b][3];
                *(float4*)&part[(((q * 4 + kqi) * 8) + b) * 64 + d4 * 4] = o;
            }
        }
        __syncthreads();
        for (int i = t; i < 1024; i += 512) {
            int d = i & 63; int bq = i >> 6; int b = bq & 7; int q2 = bq >> 3;
            float s = part[((q2 * 4 + 0) * 8 + b) * 64 + d] +
                      part[((q2 * 4 + 1) * 8 + b) * 64 + d] +
                      part[((q2 * 4 + 2) * 8 + b) * 64 + d] +
                      part[((q2 * 4 + 3) * 8 + b) * 64 + d];
            out[((size_t)b * L_ + q0 + q2) * D_ + d] = s;
        }
    }
}

// ---------------- K4: out[b][q][d] += sum_k w[b][q][k]*vp[b][k][d]
__global__ __launch_bounds__(256) void pv_kernel(
    const float* __restrict__ w, const float* __restrict__ vp, float* __restrict__ out)
{
    const int b  = blockIdx.y;
    const int q0 = blockIdx.x * 32;
    __shared__ float ws_[32][68];
    __shared__ float vs[64][64];
    const int t  = threadIdx.x;
    const int tx = t & 15;
    const int ty = t >> 4;
    float acc[2][4] = {};
    for (int kk = 0; kk < L_; kk += 64) {
        #pragma unroll
        for (int i = 0; i < 2; i++) {
            int f4 = t + 256 * i;
            int qi = f4 >> 4, kc = f4 & 15;
            float4 x = *(const float4*)(w + ((size_t)b * L_ + q0 + qi) * L_ + kk + 4 * kc);
            *(float4*)(&ws_[qi][4 * kc]) = x;
        }
        #pragma unroll
        for (int i = 0; i < 4; i++) {
            int f4 = t + 256 * i;
            int kr = f4 >> 4, dc = f4 & 15;
            float4 x = *(const float4*)(vp + ((size_t)b * L_ + kk + kr) * D_ + 4 * dc);
            *(float4*)(&vs[kr][4 * dc]) = x;
        }
        __syncthreads();
        #pragma unroll 8
        for (int k = 0; k < 64; k++) {
            float4 v4 = *(const float4*)(&vs[k][4 * tx]);
            float a0 = ws_[2 * ty][k], a1 = ws_[2 * ty + 1][k];
            acc[0][0] += a0 * v4.x; acc[0][1] += a0 * v4.y;
            acc[0][2] += a0 * v4.z; acc[0][3] += a0 * v4.w;
            acc[1][0] += a1 * v4.x; acc[1][1] += a1 * v4.y;
            acc[1][2] += a1 * v4.z; acc[1][3] += a1 * v4.w;
        }
        __syncthreads();
    }
    #pragma unroll
    for (int i = 0; i < 2; i++) {
        float* dst = out + ((size_t)b * L_ + q0 + 2 * ty + i) * D_ + 4 * tx;
        float4 o = *(const float4*)dst;
        o.x += acc[i][0]; o.y += acc[i][1]; o.z += acc[i][2]; o.w += acc[i][3];
        *(float4*)dst = o;
    }
}

extern "C" void kernel_launch(void* const* d_in, const int* in_sizes, int n_in,
                              void* d_out, int out_size, void* d_ws, size_t ws_size,
                              hipStream_t stream)
{
    const float* query = (const float*)d_in[0];
    const float* key   = (const float*)d_in[1];
    const float* value = (const float*)d_in[2];
    const float* kb    = (const float*)d_in[3];
    const float* vb    = (const float*)d_in[4];
    const float* Wq    = (const float*)d_in[5];
    const float* bq    = (const float*)d_in[6];
    const float* Wk    = (const float*)d_in[7];
    const float* bk    = (const float*)d_in[8];
    const float* Wv    = (const float*)d_in[9];
    const float* bv    = (const float*)d_in[10];
    const int*   mask  = (const int*)d_in[11];
    float* out = (float*)d_out;

    float* ws = (float*)d_ws;
    const size_t PROJ = (size_t)B_ * L_ * D_;
    float* qp = ws;
    float* kp = ws + PROJ;
    float* vp = ws + 2 * PROJ;
    float* s1 = ws + 3 * PROJ;            // 32MB; becomes w after row_kernel

    proj_kernel<<<dim3(128, 3), 256, 0, stream>>>(query, key, value,
                                                  Wq, bq, Wk, bk, Wv, bv,
                                                  qp, kp, vp);
    attn1_kernel<<<dim3(8, 8, 8), 256, 0, stream>>>(qp, kp, mask, s1);
    row_kernel<<<512, 512, 0, stream>>>(qp, kb, vb, s1, out);
    pv_kernel<<<dim3(32, 8), 256, 0, stream>>>(s1, vp, out);
}